// Round 5
// baseline (186.095 us; speedup 1.0000x reference)
//
#include <hip/hip_runtime.h>
#include <hip/hip_bf16.h>
#include <math.h>

// Problem constants (B=16, L=256, D=256, K=16384)
#define NROWS 4096               // B*L anchors / z rows
#define KMEM  16384
#define NCAND 20480              // NROWS + KMEM candidates
#define DIM   256                // feature dim
#define TM    128                // anchor rows per block
#define TN    128                // candidate cols per tile
#define BK    64                 // k-depth per LDS stage (bf16)
#define NSLICE 16                // 32 rowblocks x 16 slices = 512 blocks = 2/CU
#define COLS_PER_SLICE (NCAND / NSLICE)       // 1280
#define TILES_PER_SLICE (COLS_PER_SLICE / TN) // 10, uniform
#define INV_T  (1.0f / 0.07f)
#define SCALE2 (1.4426950408889634f / 0.07f)  // log2(e)/T
#define LN2    0.6931471805599453f
#define MERGE_STRIDE 33          // conflict-free merge: (tid*33+x)%32 distinct

typedef short  short8 __attribute__((ext_vector_type(8)));  // 8 bf16 (4 VGPRs)
typedef float  f32x4  __attribute__((ext_vector_type(4)));  // MFMA C/D
typedef unsigned short ushort_t;

// RNE float->bf16 (inputs are finite normals; no NaN path needed)
__device__ inline ushort_t f2bf(float x) {
    union { float f; unsigned u; } a; a.f = x;
    unsigned r = a.u + 0x7fff + ((a.u >> 16) & 1);
    return (ushort_t)(r >> 16);
}

// async global->LDS, 16B per lane, dest = wave-uniform base + lane*16
__device__ inline void load_lds16(const void* g, void* l) {
    __builtin_amdgcn_global_load_lds(
        (const __attribute__((address_space(1))) unsigned int*)g,
        (__attribute__((address_space(3))) unsigned int*)l, 16, 0, 0);
}

// Kernel 0: cast fp32 -> bf16 into cand = [z ; mem]; zero accumulators.
__global__ __launch_bounds__(256) void cast_kernel(
    const float* __restrict__ z, const float* __restrict__ mem,
    ushort_t* __restrict__ cand, float* __restrict__ acc_ct,
    unsigned* __restrict__ rowCnt)
{
    if (blockIdx.x == 0) {
        if (threadIdx.x == 0) {
            acc_ct[0] = 0.0f;                  // loss accumulator
            ((unsigned*)acc_ct)[1] = 0u;       // finisher arrival counter
        }
        if (threadIdx.x < 32) rowCnt[threadIdx.x] = 0u;  // per-rowblock counters
    }
    const int idx = blockIdx.x * 256 + threadIdx.x;  // float4 index, < 1310720
    const int ZQ = NROWS * DIM / 4;                  // 262144
    const float4 v = (idx < ZQ) ? ((const float4*)z)[idx]
                                : ((const float4*)mem)[idx - ZQ];
    ushort4 u; u.x = f2bf(v.x); u.y = f2bf(v.y); u.z = f2bf(v.z); u.w = f2bf(v.w);
    ((ushort4*)cand)[idx] = u;
}

// Kernel A: double-buffered MFMA flash-LSE — R0's proven 40-stage pipeline,
// exact 2-D grid (x=rowblock, y=slice; XCD swizzle reverted: R4 proved it
// cuts FETCH 3.3x but costs 9% time — drains are not load-latency-bound).
// At each BK=64 stage: FIRST issue next stage's global_load_lds into the
// other buffer, THEN this stage's 32 MFMAs, THEN one __syncthreads().
// Per-tile softmax epilogue runs while next tile's loads fly.
//
// NEW: fused finale (split-K last-block pattern). After writing its slice
// partials, each block bumps rowCnt[rowblock] (ACQ_REL, agent scope — the
// release flushes this XCD's L2, the acquire invalidates stale lines). The
// 16th arriver — no spin, no contention — combines the rowblock's 16 slice
// partials, computes the 128 pos-pair dots, and accumulates the loss; the
// 32nd finisher overall writes the scalar. Kills the 3rd launch + its gap.
__global__ __launch_bounds__(256) void mfma_lse_kernel(
    const ushort_t* __restrict__ cand, const float* __restrict__ zf,
    float* __restrict__ part_m, float* __restrict__ part_s,
    float* __restrict__ acc_ct, unsigned* __restrict__ rowCnt,
    float* __restrict__ out)
{
    __shared__ __align__(16) char smem_raw[65536];       // 2x(A 16KB + B 16KB)
    __shared__ unsigned last_flag;
    ushort_t* ldsA = (ushort_t*)smem_raw;                // [2][128*64]
    ushort_t* ldsB = ldsA + 2 * TM * BK;                 // [2][128*64]

    const int tid  = threadIdx.x;
    const int lane = tid & 63;
    const int w    = tid >> 6;        // wave 0..3
    const int wr   = w >> 1;          // wave row half (0/1)
    const int wc   = w & 1;           // wave col half
    const int quad = lane >> 4;
    const int ln   = lane & 15;
    const int bx   = blockIdx.x;      // rowblock 0..31
    const int rowBase = bx * TM;
    const int slice   = blockIdx.y;
    const int colSliceBase = slice * COLS_PER_SLICE;

    // Staging geometry (loop-invariant): wave w covers tile rows
    // [w*32, w*32+32), lane l -> row srow + u*8, chunk c = (l&7)^(srow&7)
    // (invariant across u since u*8 = 0 mod 8). XOR swizzle keeps fragment
    // ds_read_b128 conflict-free.
    const int srow = w * 32 + (lane >> 3);
    const int sc   = (lane & 7) ^ (srow & 7);
    const ushort_t* agp    = cand + (size_t)(rowBase + srow) * DIM + sc * 8;
    const ushort_t* bgbase = cand + (size_t)(colSliceBase + srow) * DIM + sc * 8;
    ushort_t* lab = ldsA + (w * 32) * BK;   // + buf*TM*BK + u*8*BK
    ushort_t* lbb = ldsB + (w * 32) * BK;

    // issue one stage's 8 async loads (tile t, k-offset kk, buffer buf)
    auto stage = [&](int t, int kk, int buf) {
        const ushort_t* ag = agp + kk;
        const ushort_t* bg = bgbase + t * (TN * DIM) + kk;
        ushort_t* la = lab + buf * (TM * BK);
        ushort_t* lb = lbb + buf * (TM * BK);
#pragma unroll
        for (int u = 0; u < 4; ++u) {
            load_lds16(ag + u * 8 * DIM, la + u * 8 * BK);
            load_lds16(bg + u * 8 * DIM, lb + u * 8 * BK);
        }
    };

    float m2[16], s[16];
#pragma unroll
    for (int i = 0; i < 16; ++i) { m2[i] = -INFINITY; s[i] = 0.0f; }

    f32x4 acc[4][4];
#pragma unroll
    for (int ti = 0; ti < 4; ++ti)
#pragma unroll
        for (int tj = 0; tj < 4; ++tj) acc[ti][tj] = (f32x4)0.0f;

    stage(0, 0, 0);        // prologue: stage 0 -> buffer 0
    __syncthreads();

    for (int t = 0; t < TILES_PER_SLICE; ++t) {
#pragma unroll
        for (int q = 0; q < 4; ++q) {
            const int buf = q & 1;          // s = 4t+q -> buf = s&1 = q&1
            // prefetch next stage into the other buffer (in flight across
            // this stage's compute; drained by the barrier below)
            if (q < 3)                       stage(t,     (q + 1) * BK, buf ^ 1);
            else if (t + 1 < TILES_PER_SLICE) stage(t + 1, 0,           buf ^ 1);

            // compute stage s from buffer buf: 2 k-steps x 16 MFMA
            const ushort_t* la = ldsA + buf * (TM * BK);
            const ushort_t* lb = ldsB + buf * (TM * BK);
#pragma unroll
            for (int ks = 0; ks < 2; ++ks) {
                short8 af[4], bfr[4];
#pragma unroll
                for (int ti = 0; ti < 4; ++ti) {
                    const int row = wr * 64 + ti * 16 + ln;
                    const int p = row * 8 + ((ks * 4 + quad) ^ (row & 7));
                    af[ti] = *(const short8*)(la + p * 8);
                }
#pragma unroll
                for (int tj = 0; tj < 4; ++tj) {
                    const int col = wc * 64 + tj * 16 + ln;
                    const int p = col * 8 + ((ks * 4 + quad) ^ (col & 7));
                    bfr[tj] = *(const short8*)(lb + p * 8);
                }
#pragma unroll
                for (int ti = 0; ti < 4; ++ti)
#pragma unroll
                    for (int tj = 0; tj < 4; ++tj)
                        acc[ti][tj] = __builtin_amdgcn_mfma_f32_16x16x32_bf16(
                            af[ti], bfr[tj], acc[ti][tj], 0, 0, 0);
            }

            if (q == 3) {
                // Epilogue for tile t (runs while tile t+1's loads fly).
                // C/D layout: col = ln+16*tj+64*wc, row = quad*4+reg+16*ti+64*wr
                const int colBase = colSliceBase + t * TN;
                const bool hasDiag =
                    (colBase < rowBase + TM) && (rowBase < colBase + TN);
#pragma unroll
                for (int ti = 0; ti < 4; ++ti) {
#pragma unroll
                    for (int r = 0; r < 4; ++r) {
                        const int idx = ti * 4 + r;
                        float v0 = acc[ti][0][r], v1 = acc[ti][1][r];
                        float v2 = acc[ti][2][r], v3 = acc[ti][3][r];
                        if (hasDiag) {
                            const int grow = rowBase + wr * 64 + ti * 16 + quad * 4 + r;
                            const int gc0  = colBase + wc * 64 + ln;
                            if (gc0      == grow) v0 = -3.0e38f;  // mask self
                            if (gc0 + 16 == grow) v1 = -3.0e38f;
                            if (gc0 + 32 == grow) v2 = -3.0e38f;
                            if (gc0 + 48 == grow) v3 = -3.0e38f;
                        }
                        const float tmax = fmaxf(fmaxf(v0, v1), fmaxf(v2, v3)) * SCALE2;
                        const float mo = m2[idx];
                        const float mn = fmaxf(mo, tmax);
                        const float sc2 = __builtin_amdgcn_exp2f(mo - mn);
                        s[idx] = s[idx] * sc2
                               + __builtin_amdgcn_exp2f(fmaf(v0, SCALE2, -mn))
                               + __builtin_amdgcn_exp2f(fmaf(v1, SCALE2, -mn))
                               + __builtin_amdgcn_exp2f(fmaf(v2, SCALE2, -mn))
                               + __builtin_amdgcn_exp2f(fmaf(v3, SCALE2, -mn));
                        m2[idx] = mn;
                        acc[ti][0][r] = 0.0f; acc[ti][1][r] = 0.0f;
                        acc[ti][2][r] = 0.0f; acc[ti][3][r] = 0.0f;
                    }
                }
            }
            __syncthreads();   // publishes prefetched stage; frees old buffer
        }
    }

    // Cross-lane merge: 32 partials per row (16 ln x 2 wc), stride-33 overlay
    // (conflict-free: (tid*33+x)%32 = (tid+x)%32). Loop barrier above already
    // separated the last compute from this smem reuse.
    float* smf = (float*)smem_raw;         // [128][33] m partials
    float* ssf = smf + TM * MERGE_STRIDE;  // [128][33] s partials
    const int p = wc * 16 + ln;
#pragma unroll
    for (int ti = 0; ti < 4; ++ti)
#pragma unroll
        for (int r = 0; r < 4; ++r) {
            const int rl = wr * 64 + ti * 16 + quad * 4 + r;
            smf[rl * MERGE_STRIDE + p] = m2[ti * 4 + r];
            ssf[rl * MERGE_STRIDE + p] = s[ti * 4 + r];
        }
    __syncthreads();
    if (tid < TM) {
        float M = -INFINITY;
#pragma unroll
        for (int x = 0; x < 32; ++x) M = fmaxf(M, smf[tid * MERGE_STRIDE + x]);
        float S = 0.0f;
#pragma unroll
        for (int x = 0; x < 32; ++x)
            S += ssf[tid * MERGE_STRIDE + x]
               * __builtin_amdgcn_exp2f(smf[tid * MERGE_STRIDE + x] - M);
        part_m[(size_t)(rowBase + tid) * NSLICE + slice] = M;
        part_s[(size_t)(rowBase + tid) * NSLICE + slice] = S;
    }

    // ---- Fused finale: split-K last-block reduction (no spin, no barrier) ----
    __syncthreads();   // every wave's part stores issued (vmcnt drained per wave)
    if (tid == 0) {
        __threadfence();   // write back this XCD's L2 -> partials device-visible
        const unsigned old = __hip_atomic_fetch_add(
            &rowCnt[bx], 1u, __ATOMIC_ACQ_REL, __HIP_MEMORY_SCOPE_AGENT);
        last_flag = (old == NSLICE - 1) ? 1u : 0u;   // acquire inv'd stale lines
    }
    __syncthreads();
    if (!last_flag) return;

    // This block is the 16th (last) for rows [rowBase, rowBase+128): combine
    // slice partials + exact fp32 pos-dot + loss partial. Wave-per-row.
    float wsum = 0.0f;
#pragma unroll 1
    for (int it = 0; it < TM / 4; ++it) {
        const int i = rowBase + it * 4 + w;     // row (wave-uniform)
        if ((i & 255) != 255) {                 // valid pair (guards i=4095 too)
            const float4 av = ((const float4*)(zf + (size_t)i * DIM))[lane];
            const float4 bv = ((const float4*)(zf + (size_t)(i + 1) * DIM))[lane];
            float d = av.x * bv.x + av.y * bv.y + av.z * bv.z + av.w * bv.w;
#pragma unroll
            for (int off = 32; off > 0; off >>= 1) d += __shfl_xor(d, off);
            const float m  = (lane < NSLICE)
                ? part_m[(size_t)i * NSLICE + lane] : -INFINITY;
            const float sv = (lane < NSLICE)
                ? part_s[(size_t)i * NSLICE + lane] : 0.0f;
            float M = m;
#pragma unroll
            for (int off = 8; off > 0; off >>= 1) M = fmaxf(M, __shfl_xor(M, off));
            float S = (lane < NSLICE) ? sv * __builtin_amdgcn_exp2f(m - M) : 0.0f;
#pragma unroll
            for (int off = 8; off > 0; off >>= 1) S += __shfl_xor(S, off);
            const float lse = LN2 * (M + __builtin_amdgcn_logf(S)); // v_log = log2
            wsum += lse - d * INV_T;
        }
    }
    float* redf = (float*)smem_raw;            // reuse (sync'd above)
    if (lane == 0) redf[w] = wsum;
    __syncthreads();
    if (tid == 0) {
        const float r = redf[0] + redf[1] + redf[2] + redf[3];
        atomicAdd(&acc_ct[0], r);              // device-scope float atomic
        __threadfence();
        const unsigned old = atomicAdd((unsigned*)&acc_ct[1], 1u);
        if (old == 31) {                       // 32nd finisher writes scalar
            const float total = atomicAdd(&acc_ct[0], 0.0f);  // coherent read
            out[0] = total / 4080.0f;          // B*(L-1) valid pairs
        }
    }
}

extern "C" void kernel_launch(void* const* d_in, const int* in_sizes, int n_in,
                              void* d_out, int out_size, void* d_ws, size_t ws_size,
                              hipStream_t stream) {
    const float* z   = (const float*)d_in[0];   // [4096, 256]
    // d_in[1] = va_values: dead code in the reference, unused.
    const float* mem = (const float*)d_in[2];   // [16384, 256]

    // ws layout: cand bf16 [20480*256] | part_m f32 [4096*16]
    //          | part_s f32 [4096*16] | acc_ct f32[2] | rowCnt u32[32]
    ushort_t* cand = (ushort_t*)d_ws;
    float* part_m  = (float*)(cand + (size_t)NCAND * DIM);
    float* part_s  = part_m + (size_t)NROWS * NSLICE;
    float* acc_ct  = part_s + (size_t)NROWS * NSLICE;
    unsigned* rowCnt = (unsigned*)(acc_ct + 2);

    const int castBlocks = NCAND * DIM / 4 / 256;   // 5120
    cast_kernel<<<dim3(castBlocks), dim3(256), 0, stream>>>(
        z, mem, cand, acc_ct, rowCnt);
    mfma_lse_kernel<<<dim3(NROWS / TM, NSLICE), dim3(256), 0, stream>>>(
        cand, z, part_m, part_s, acc_ct, rowCnt, (float*)d_out);
}

// Round 6
// 182.718 us; speedup vs baseline: 1.0185x; 1.0185x over previous
//
#include <hip/hip_runtime.h>
#include <hip/hip_bf16.h>
#include <math.h>

// Problem constants (B=16, L=256, D=256, K=16384)
#define NROWS 4096               // B*L anchors / z rows
#define KMEM  16384
#define NCAND 20480              // NROWS + KMEM candidates
#define DIM   256                // feature dim
#define TM    128                // anchor rows per block
#define TN    128                // candidate cols per tile
#define BK    64                 // k-depth per LDS stage (bf16)
#define NSLICE 16                // 32 rowblocks x 16 slices = 512 blocks = 2/CU
#define COLS_PER_SLICE (NCAND / NSLICE)       // 1280
#define TILES_PER_SLICE (COLS_PER_SLICE / TN) // 10, uniform
#define INV_T  (1.0f / 0.07f)
#define SCALE2 (1.4426950408889634f / 0.07f)  // log2(e)/T
#define LN2    0.6931471805599453f
#define MERGE_STRIDE 33          // conflict-free merge: (tid*33+x)%32 distinct

typedef short  short8 __attribute__((ext_vector_type(8)));  // 8 bf16 (4 VGPRs)
typedef float  f32x4  __attribute__((ext_vector_type(4)));  // MFMA C/D
typedef unsigned short ushort_t;

// RNE float->bf16 (inputs are finite normals; no NaN path needed)
__device__ inline ushort_t f2bf(float x) {
    union { float f; unsigned u; } a; a.f = x;
    unsigned r = a.u + 0x7fff + ((a.u >> 16) & 1);
    return (ushort_t)(r >> 16);
}

// async global->LDS, 16B per lane, dest = wave-uniform base + lane*16
__device__ inline void load_lds16(const void* g, void* l) {
    __builtin_amdgcn_global_load_lds(
        (const __attribute__((address_space(1))) unsigned int*)g,
        (__attribute__((address_space(3))) unsigned int*)l, 16, 0, 0);
}

// Kernel 0: cast fp32 -> bf16 into cand = [z ; mem]; zero accumulators.
__global__ __launch_bounds__(256) void cast_kernel(
    const float* __restrict__ z, const float* __restrict__ mem,
    ushort_t* __restrict__ cand, float* __restrict__ acc_ct,
    unsigned* __restrict__ rowCnt)
{
    if (blockIdx.x == 0) {
        if (threadIdx.x == 0) {
            acc_ct[0] = 0.0f;                  // loss accumulator
            ((unsigned*)acc_ct)[1] = 0u;       // finisher arrival counter
        }
        if (threadIdx.x < 32) rowCnt[threadIdx.x] = 0u;  // per-rowblock counters
    }
    const int idx = blockIdx.x * 256 + threadIdx.x;  // float4 index, < 1310720
    const int ZQ = NROWS * DIM / 4;                  // 262144
    const float4 v = (idx < ZQ) ? ((const float4*)z)[idx]
                                : ((const float4*)mem)[idx - ZQ];
    ushort4 u; u.x = f2bf(v.x); u.y = f2bf(v.y); u.z = f2bf(v.z); u.w = f2bf(v.w);
    ((ushort4*)cand)[idx] = u;
}

// Kernel A: double-buffered MFMA flash-LSE — R0's proven 40-stage pipeline,
// exact 2-D grid. At each BK=64 stage: FIRST issue next stage's
// global_load_lds into the other buffer, THEN this stage's 32 MFMAs, THEN one
// __syncthreads(). Per-tile softmax epilogue runs while next tile's loads fly.
//
// Fused finale (split-K last-block pattern): after writing slice partials,
// each block bumps rowCnt[rowblock] (ACQ_REL agent scope; release flushes
// this XCD's L2, acquire invalidates stale lines). The 16th arriver — no
// spin — combines the rowblock's 16 slice partials, computes the 128
// pos-pair dots, accumulates the loss; 32nd finisher writes the scalar.
//
// CRITICAL (R5 lesson): total static LDS must be EXACTLY 65536 B. 66048 B
// (one extra __shared__ word) dropped co-residency to 1 block/CU and doubled
// kernel time. The finale's flag is overlaid inside smem_raw instead.
__global__ __launch_bounds__(256) void mfma_lse_kernel(
    const ushort_t* __restrict__ cand, const float* __restrict__ zf,
    float* __restrict__ part_m, float* __restrict__ part_s,
    float* __restrict__ acc_ct, unsigned* __restrict__ rowCnt,
    float* __restrict__ out)
{
    __shared__ __align__(16) char smem_raw[65536];       // 2x(A 16KB + B 16KB)
    ushort_t* ldsA = (ushort_t*)smem_raw;                // [2][128*64]
    ushort_t* ldsB = ldsA + 2 * TM * BK;                 // [2][128*64]

    const int tid  = threadIdx.x;
    const int lane = tid & 63;
    const int w    = tid >> 6;        // wave 0..3
    const int wr   = w >> 1;          // wave row half (0/1)
    const int wc   = w & 1;           // wave col half
    const int quad = lane >> 4;
    const int ln   = lane & 15;
    const int bx   = blockIdx.x;      // rowblock 0..31
    const int rowBase = bx * TM;
    const int slice   = blockIdx.y;
    const int colSliceBase = slice * COLS_PER_SLICE;

    // Staging geometry (loop-invariant): wave w covers tile rows
    // [w*32, w*32+32), lane l -> row srow + u*8, chunk c = (l&7)^(srow&7)
    // (invariant across u since u*8 = 0 mod 8). XOR swizzle keeps fragment
    // ds_read_b128 conflict-free.
    const int srow = w * 32 + (lane >> 3);
    const int sc   = (lane & 7) ^ (srow & 7);
    const ushort_t* agp    = cand + (size_t)(rowBase + srow) * DIM + sc * 8;
    const ushort_t* bgbase = cand + (size_t)(colSliceBase + srow) * DIM + sc * 8;
    ushort_t* lab = ldsA + (w * 32) * BK;   // + buf*TM*BK + u*8*BK
    ushort_t* lbb = ldsB + (w * 32) * BK;

    // issue one stage's 8 async loads (tile t, k-offset kk, buffer buf)
    auto stage = [&](int t, int kk, int buf) {
        const ushort_t* ag = agp + kk;
        const ushort_t* bg = bgbase + t * (TN * DIM) + kk;
        ushort_t* la = lab + buf * (TM * BK);
        ushort_t* lb = lbb + buf * (TM * BK);
#pragma unroll
        for (int u = 0; u < 4; ++u) {
            load_lds16(ag + u * 8 * DIM, la + u * 8 * BK);
            load_lds16(bg + u * 8 * DIM, lb + u * 8 * BK);
        }
    };

    float m2[16], s[16];
#pragma unroll
    for (int i = 0; i < 16; ++i) { m2[i] = -INFINITY; s[i] = 0.0f; }

    f32x4 acc[4][4];
#pragma unroll
    for (int ti = 0; ti < 4; ++ti)
#pragma unroll
        for (int tj = 0; tj < 4; ++tj) acc[ti][tj] = (f32x4)0.0f;

    stage(0, 0, 0);        // prologue: stage 0 -> buffer 0
    __syncthreads();

    for (int t = 0; t < TILES_PER_SLICE; ++t) {
#pragma unroll
        for (int q = 0; q < 4; ++q) {
            const int buf = q & 1;          // s = 4t+q -> buf = s&1 = q&1
            // prefetch next stage into the other buffer (in flight across
            // this stage's compute; drained by the barrier below)
            if (q < 3)                       stage(t,     (q + 1) * BK, buf ^ 1);
            else if (t + 1 < TILES_PER_SLICE) stage(t + 1, 0,           buf ^ 1);

            // compute stage s from buffer buf: 2 k-steps x 16 MFMA
            const ushort_t* la = ldsA + buf * (TM * BK);
            const ushort_t* lb = ldsB + buf * (TM * BK);
#pragma unroll
            for (int ks = 0; ks < 2; ++ks) {
                short8 af[4], bfr[4];
#pragma unroll
                for (int ti = 0; ti < 4; ++ti) {
                    const int row = wr * 64 + ti * 16 + ln;
                    const int p = row * 8 + ((ks * 4 + quad) ^ (row & 7));
                    af[ti] = *(const short8*)(la + p * 8);
                }
#pragma unroll
                for (int tj = 0; tj < 4; ++tj) {
                    const int col = wc * 64 + tj * 16 + ln;
                    const int p = col * 8 + ((ks * 4 + quad) ^ (col & 7));
                    bfr[tj] = *(const short8*)(lb + p * 8);
                }
#pragma unroll
                for (int ti = 0; ti < 4; ++ti)
#pragma unroll
                    for (int tj = 0; tj < 4; ++tj)
                        acc[ti][tj] = __builtin_amdgcn_mfma_f32_16x16x32_bf16(
                            af[ti], bfr[tj], acc[ti][tj], 0, 0, 0);
            }

            if (q == 3) {
                // Epilogue for tile t (runs while tile t+1's loads fly).
                // C/D layout: col = ln+16*tj+64*wc, row = quad*4+reg+16*ti+64*wr
                const int colBase = colSliceBase + t * TN;
                const bool hasDiag =
                    (colBase < rowBase + TM) && (rowBase < colBase + TN);
#pragma unroll
                for (int ti = 0; ti < 4; ++ti) {
#pragma unroll
                    for (int r = 0; r < 4; ++r) {
                        const int idx = ti * 4 + r;
                        float v0 = acc[ti][0][r], v1 = acc[ti][1][r];
                        float v2 = acc[ti][2][r], v3 = acc[ti][3][r];
                        if (hasDiag) {
                            const int grow = rowBase + wr * 64 + ti * 16 + quad * 4 + r;
                            const int gc0  = colBase + wc * 64 + ln;
                            if (gc0      == grow) v0 = -3.0e38f;  // mask self
                            if (gc0 + 16 == grow) v1 = -3.0e38f;
                            if (gc0 + 32 == grow) v2 = -3.0e38f;
                            if (gc0 + 48 == grow) v3 = -3.0e38f;
                        }
                        const float tmax = fmaxf(fmaxf(v0, v1), fmaxf(v2, v3)) * SCALE2;
                        const float mo = m2[idx];
                        const float mn = fmaxf(mo, tmax);
                        const float sc2 = __builtin_amdgcn_exp2f(mo - mn);
                        s[idx] = s[idx] * sc2
                               + __builtin_amdgcn_exp2f(fmaf(v0, SCALE2, -mn))
                               + __builtin_amdgcn_exp2f(fmaf(v1, SCALE2, -mn))
                               + __builtin_amdgcn_exp2f(fmaf(v2, SCALE2, -mn))
                               + __builtin_amdgcn_exp2f(fmaf(v3, SCALE2, -mn));
                        m2[idx] = mn;
                        acc[ti][0][r] = 0.0f; acc[ti][1][r] = 0.0f;
                        acc[ti][2][r] = 0.0f; acc[ti][3][r] = 0.0f;
                    }
                }
            }
            __syncthreads();   // publishes prefetched stage; frees old buffer
        }
    }

    // Cross-lane merge: 32 partials per row (16 ln x 2 wc), stride-33 overlay
    // (conflict-free: (tid*33+x)%32 = (tid+x)%32). Loop barrier above already
    // separated the last compute from this smem reuse.
    float* smf = (float*)smem_raw;         // [128][33] m partials
    float* ssf = smf + TM * MERGE_STRIDE;  // [128][33] s partials
    const int p = wc * 16 + ln;
#pragma unroll
    for (int ti = 0; ti < 4; ++ti)
#pragma unroll
        for (int r = 0; r < 4; ++r) {
            const int rl = wr * 64 + ti * 16 + quad * 4 + r;
            smf[rl * MERGE_STRIDE + p] = m2[ti * 4 + r];
            ssf[rl * MERGE_STRIDE + p] = s[ti * 4 + r];
        }
    __syncthreads();
    if (tid < TM) {
        float M = -INFINITY;
#pragma unroll
        for (int x = 0; x < 32; ++x) M = fmaxf(M, smf[tid * MERGE_STRIDE + x]);
        float S = 0.0f;
#pragma unroll
        for (int x = 0; x < 32; ++x)
            S += ssf[tid * MERGE_STRIDE + x]
               * __builtin_amdgcn_exp2f(smf[tid * MERGE_STRIDE + x] - M);
        part_m[(size_t)(rowBase + tid) * NSLICE + slice] = M;
        part_s[(size_t)(rowBase + tid) * NSLICE + slice] = S;
    }

    // ---- Fused finale: split-K last-block reduction (no spin, no barrier).
    // Flag lives INSIDE smem_raw (dead space past the merge overlay) — zero
    // extra LDS (R5: +512B LDS allocation -> 1 block/CU -> 2x slowdown).
    unsigned* lastf = (unsigned*)(smem_raw + 65532);
    __syncthreads();   // part stores issued; smem_raw free for reuse
    if (tid == 0) {
        __threadfence();   // write back this XCD's L2 -> partials device-visible
        const unsigned old = __hip_atomic_fetch_add(
            &rowCnt[bx], 1u, __ATOMIC_ACQ_REL, __HIP_MEMORY_SCOPE_AGENT);
        *lastf = (old == NSLICE - 1) ? 1u : 0u;   // acquire inv'd stale lines
    }
    __syncthreads();
    if (!*lastf) return;

    // This block is the 16th (last) for rows [rowBase, rowBase+128): combine
    // slice partials + exact fp32 pos-dot + loss partial. Wave-per-row.
    float wsum = 0.0f;
#pragma unroll 1
    for (int it = 0; it < TM / 4; ++it) {
        const int i = rowBase + it * 4 + w;     // row (wave-uniform)
        if ((i & 255) != 255) {                 // valid pair (guards i=4095 too)
            const float4 av = ((const float4*)(zf + (size_t)i * DIM))[lane];
            const float4 bv = ((const float4*)(zf + (size_t)(i + 1) * DIM))[lane];
            float d = av.x * bv.x + av.y * bv.y + av.z * bv.z + av.w * bv.w;
#pragma unroll
            for (int off = 32; off > 0; off >>= 1) d += __shfl_xor(d, off);
            const float m  = (lane < NSLICE)
                ? part_m[(size_t)i * NSLICE + lane] : -INFINITY;
            const float sv = (lane < NSLICE)
                ? part_s[(size_t)i * NSLICE + lane] : 0.0f;
            float M = m;
#pragma unroll
            for (int off = 8; off > 0; off >>= 1) M = fmaxf(M, __shfl_xor(M, off));
            float S = (lane < NSLICE) ? sv * __builtin_amdgcn_exp2f(m - M) : 0.0f;
#pragma unroll
            for (int off = 8; off > 0; off >>= 1) S += __shfl_xor(S, off);
            const float lse = LN2 * (M + __builtin_amdgcn_logf(S)); // v_log = log2
            wsum += lse - d * INV_T;
        }
    }
    float* redf = (float*)smem_raw;            // reuse (sync'd above)
    if (lane == 0) redf[w] = wsum;
    __syncthreads();
    if (tid == 0) {
        const float r = redf[0] + redf[1] + redf[2] + redf[3];
        atomicAdd(&acc_ct[0], r);              // device-scope float atomic
        __threadfence();
        const unsigned old = atomicAdd((unsigned*)&acc_ct[1], 1u);
        if (old == 31) {                       // 32nd finisher writes scalar
            const float total = atomicAdd(&acc_ct[0], 0.0f);  // coherent read
            out[0] = total / 4080.0f;          // B*(L-1) valid pairs
        }
    }
}

extern "C" void kernel_launch(void* const* d_in, const int* in_sizes, int n_in,
                              void* d_out, int out_size, void* d_ws, size_t ws_size,
                              hipStream_t stream) {
    const float* z   = (const float*)d_in[0];   // [4096, 256]
    // d_in[1] = va_values: dead code in the reference, unused.
    const float* mem = (const float*)d_in[2];   // [16384, 256]

    // ws layout: cand bf16 [20480*256] | part_m f32 [4096*16]
    //          | part_s f32 [4096*16] | acc_ct f32[2] | rowCnt u32[32]
    ushort_t* cand = (ushort_t*)d_ws;
    float* part_m  = (float*)(cand + (size_t)NCAND * DIM);
    float* part_s  = part_m + (size_t)NROWS * NSLICE;
    float* acc_ct  = part_s + (size_t)NROWS * NSLICE;
    unsigned* rowCnt = (unsigned*)(acc_ct + 2);

    const int castBlocks = NCAND * DIM / 4 / 256;   // 5120
    cast_kernel<<<dim3(castBlocks), dim3(256), 0, stream>>>(
        z, mem, cand, acc_ct, rowCnt);
    mfma_lse_kernel<<<dim3(NROWS / TM, NSLICE), dim3(256), 0, stream>>>(
        cand, z, part_m, part_s, acc_ct, rowCnt, (float*)d_out);
}

// Round 7
// 158.680 us; speedup vs baseline: 1.1728x; 1.1515x over previous
//
#include <hip/hip_runtime.h>
#include <hip/hip_bf16.h>
#include <math.h>

// Problem constants (B=16, L=256, D=256, K=16384)
#define NROWS 4096               // B*L anchors / z rows
#define KMEM  16384
#define NCAND 20480              // NROWS + KMEM candidates
#define DIM   256                // feature dim
#define TM    128                // anchor rows per block
#define TN    128                // candidate cols per tile
#define BK    64                 // k-depth per LDS stage (bf16)
#define NSLICE 16                // 32 rowblocks x 16 slices = 512 blocks = 2/CU
#define COLS_PER_SLICE (NCAND / NSLICE)       // 1280
#define TILES_PER_SLICE (COLS_PER_SLICE / TN) // 10, uniform
#define INV_T  (1.0f / 0.07f)
#define SCALE2 (1.4426950408889634f / 0.07f)  // log2(e)/T
#define LN2    0.6931471805599453f
#define MERGE_STRIDE 33          // conflict-free merge: (tid*33+x)%32 distinct
#define SMEM_BYTES 33792         // max(B dbuf 32768, merge overlay 33792)

typedef short  short8 __attribute__((ext_vector_type(8)));  // 8 bf16 (4 VGPRs)
typedef float  f32x4  __attribute__((ext_vector_type(4)));  // MFMA C/D
typedef unsigned short ushort_t;

// RNE float->bf16 (inputs are finite normals; no NaN path needed)
__device__ inline ushort_t f2bf(float x) {
    union { float f; unsigned u; } a; a.f = x;
    unsigned r = a.u + 0x7fff + ((a.u >> 16) & 1);
    return (ushort_t)(r >> 16);
}

// async global->LDS, 16B per lane, dest = wave-uniform base + lane*16
__device__ inline void load_lds16(const void* g, void* l) {
    __builtin_amdgcn_global_load_lds(
        (const __attribute__((address_space(1))) unsigned int*)g,
        (__attribute__((address_space(3))) unsigned int*)l, 16, 0, 0);
}

// Kernel 0: cast fp32 -> bf16 into cand = [z ; mem]; zero loss accumulator.
__global__ __launch_bounds__(256) void cast_kernel(
    const float* __restrict__ z, const float* __restrict__ mem,
    ushort_t* __restrict__ cand, float* __restrict__ acc_ct)
{
    if (blockIdx.x == 0 && threadIdx.x == 0) {
        acc_ct[0] = 0.0f;                      // loss accumulator
        ((unsigned*)acc_ct)[1] = 0u;           // arrival counter
    }
    const int idx = blockIdx.x * 256 + threadIdx.x;  // float4 index, < 1310720
    const int ZQ = NROWS * DIM / 4;                  // 262144
    const float4 v = (idx < ZQ) ? ((const float4*)z)[idx]
                                : ((const float4*)mem)[idx - ZQ];
    ushort4 u; u.x = f2bf(v.x); u.y = f2bf(v.y); u.z = f2bf(v.z); u.w = f2bf(v.w);
    ((ushort4*)cand)[idx] = u;
}

// Kernel A: double-buffered MFMA flash-LSE, R0's proven 40-stage pipeline
// with A HOISTED INTO REGISTERS. The A-panel (128x256 bf16) is invariant
// across all 10 B-tiles; R0 re-staged and re-read it every stage (half of
// all staging loads + half of all ds_reads = pure waste). Here a 4-step
// prologue pipelines A through the same double buffer into af[4][8]
// (32 x short8 = 128 VGPRs, statically indexed), and the 40-stage main loop
// stages ONLY B (4 async loads/stage, halved drain depth) and reads only
// b-frags from LDS (8 ds_read_b128/stage instead of 16).
// R5/R6 lesson: fused finale cost ~60 us twice -> reverted to 3 kernels.
__global__ __launch_bounds__(256, 2) void mfma_lse_kernel(
    const ushort_t* __restrict__ cand,
    float* __restrict__ part_m, float* __restrict__ part_s)
{
    __shared__ __align__(16) char smem_raw[SMEM_BYTES];  // B dbuf [2][128*64]
    ushort_t* ldsB = (ushort_t*)smem_raw;

    const int tid  = threadIdx.x;
    const int lane = tid & 63;
    const int w    = tid >> 6;        // wave 0..3
    const int wr   = w >> 1;          // wave row half (0/1)
    const int wc   = w & 1;           // wave col half
    const int quad = lane >> 4;
    const int ln   = lane & 15;
    const int rowBase = blockIdx.x * TM;
    const int slice   = blockIdx.y;
    const int colSliceBase = slice * COLS_PER_SLICE;

    // Staging geometry (loop-invariant): wave w covers tile rows
    // [w*32, w*32+32), lane l -> row srow + u*8, chunk c = (l&7)^(srow&7)
    // (invariant across u since u*8 = 0 mod 8). XOR swizzle keeps fragment
    // ds_read_b128 conflict-free.
    const int srow = w * 32 + (lane >> 3);
    const int sc   = (lane & 7) ^ (srow & 7);
    const ushort_t* agp    = cand + (size_t)(rowBase + srow) * DIM + sc * 8;
    const ushort_t* bgbase = cand + (size_t)(colSliceBase + srow) * DIM + sc * 8;
    ushort_t* lbb = ldsB + (w * 32) * BK;   // + buf*TM*BK + u*8*BK

    // stage one 16KB A-chunk (k-offset kk) or B-stage (tile t, k-offset kk)
    auto stageA = [&](int kk, int buf) {
        const ushort_t* ag = agp + kk;
        ushort_t* lb = lbb + buf * (TM * BK);
#pragma unroll
        for (int u = 0; u < 4; ++u)
            load_lds16(ag + u * 8 * DIM, lb + u * 8 * BK);
    };
    auto stageB = [&](int t, int kk, int buf) {
        const ushort_t* bg = bgbase + t * (TN * DIM) + kk;
        ushort_t* lb = lbb + buf * (TM * BK);
#pragma unroll
        for (int u = 0; u < 4; ++u)
            load_lds16(bg + u * 8 * DIM, lb + u * 8 * BK);
    };

    float m2[16], s[16];
#pragma unroll
    for (int i = 0; i < 16; ++i) { m2[i] = -INFINITY; s[i] = 0.0f; }

    f32x4 acc[4][4];
#pragma unroll
    for (int ti = 0; ti < 4; ++ti)
#pragma unroll
        for (int tj = 0; tj < 4; ++tj) acc[ti][tj] = (f32x4)0.0f;

    // ---- A-prologue: pipeline the 4 A-chunks through the double buffer into
    // registers. af[ti][c*2+ks] = frag for row wr*64+ti*16+ln, k-chunk
    // c*64 + ks*32 + quad*8. All indices compile-time constant (no scratch).
    short8 af[4][8];
    stageA(0, 0);
    __syncthreads();
#pragma unroll
    for (int c = 0; c < 4; ++c) {
        const int buf = c & 1;
        if (c < 3) stageA((c + 1) * BK, buf ^ 1);
        else       stageB(0, 0, buf ^ 1);        // first B stage -> buf0
        const ushort_t* la = ldsB + buf * (TM * BK);
#pragma unroll
        for (int ks = 0; ks < 2; ++ks)
#pragma unroll
            for (int ti = 0; ti < 4; ++ti) {
                const int row = wr * 64 + ti * 16 + ln;
                const int p = row * 8 + ((ks * 4 + quad) ^ (row & 7));
                af[ti][c * 2 + ks] = *(const short8*)(la + p * 8);
            }
        __syncthreads();
    }
    // parity: B(t=0,kk=0) now in buf0; main loop stage s=4t+q uses buf=q&1.

    for (int t = 0; t < TILES_PER_SLICE; ++t) {
#pragma unroll
        for (int q = 0; q < 4; ++q) {
            const int buf = q & 1;
            // prefetch next B stage into the other buffer (in flight across
            // this stage's compute; drained by the barrier below)
            if (q < 3)                       stageB(t,     (q + 1) * BK, buf ^ 1);
            else if (t + 1 < TILES_PER_SLICE) stageB(t + 1, 0,           buf ^ 1);

            // compute stage from buffer buf: 2 k-steps x 16 MFMA, A from regs
            const ushort_t* lb = ldsB + buf * (TM * BK);
#pragma unroll
            for (int ks = 0; ks < 2; ++ks) {
                short8 bfr[4];
#pragma unroll
                for (int tj = 0; tj < 4; ++tj) {
                    const int col = wc * 64 + tj * 16 + ln;
                    const int p = col * 8 + ((ks * 4 + quad) ^ (col & 7));
                    bfr[tj] = *(const short8*)(lb + p * 8);
                }
#pragma unroll
                for (int ti = 0; ti < 4; ++ti)
#pragma unroll
                    for (int tj = 0; tj < 4; ++tj)
                        acc[ti][tj] = __builtin_amdgcn_mfma_f32_16x16x32_bf16(
                            af[ti][q * 2 + ks], bfr[tj], acc[ti][tj], 0, 0, 0);
            }

            if (q == 3) {
                // Epilogue for tile t (runs while tile t+1's loads fly).
                // C/D layout: col = ln+16*tj+64*wc, row = quad*4+reg+16*ti+64*wr
                const int colBase = colSliceBase + t * TN;
                const bool hasDiag =
                    (colBase < rowBase + TM) && (rowBase < colBase + TN);
#pragma unroll
                for (int ti = 0; ti < 4; ++ti) {
#pragma unroll
                    for (int r = 0; r < 4; ++r) {
                        const int idx = ti * 4 + r;
                        float v0 = acc[ti][0][r], v1 = acc[ti][1][r];
                        float v2 = acc[ti][2][r], v3 = acc[ti][3][r];
                        if (hasDiag) {
                            const int grow = rowBase + wr * 64 + ti * 16 + quad * 4 + r;
                            const int gc0  = colBase + wc * 64 + ln;
                            if (gc0      == grow) v0 = -3.0e38f;  // mask self
                            if (gc0 + 16 == grow) v1 = -3.0e38f;
                            if (gc0 + 32 == grow) v2 = -3.0e38f;
                            if (gc0 + 48 == grow) v3 = -3.0e38f;
                        }
                        const float tmax = fmaxf(fmaxf(v0, v1), fmaxf(v2, v3)) * SCALE2;
                        const float mo = m2[idx];
                        const float mn = fmaxf(mo, tmax);
                        const float sc2 = __builtin_amdgcn_exp2f(mo - mn);
                        s[idx] = s[idx] * sc2
                               + __builtin_amdgcn_exp2f(fmaf(v0, SCALE2, -mn))
                               + __builtin_amdgcn_exp2f(fmaf(v1, SCALE2, -mn))
                               + __builtin_amdgcn_exp2f(fmaf(v2, SCALE2, -mn))
                               + __builtin_amdgcn_exp2f(fmaf(v3, SCALE2, -mn));
                        m2[idx] = mn;
                        acc[ti][0][r] = 0.0f; acc[ti][1][r] = 0.0f;
                        acc[ti][2][r] = 0.0f; acc[ti][3][r] = 0.0f;
                    }
                }
            }
            __syncthreads();   // publishes prefetched stage; frees old buffer
        }
    }

    // Cross-lane merge: 32 partials per row (16 ln x 2 wc), stride-33 overlay
    // (conflict-free: (tid*33+x)%32 = (tid+x)%32). Loop barrier above already
    // separated the last compute from this smem reuse.
    float* smf = (float*)smem_raw;         // [128][33] m partials
    float* ssf = smf + TM * MERGE_STRIDE;  // [128][33] s partials (33792B total)
    const int p = wc * 16 + ln;
#pragma unroll
    for (int ti = 0; ti < 4; ++ti)
#pragma unroll
        for (int r = 0; r < 4; ++r) {
            const int rl = wr * 64 + ti * 16 + quad * 4 + r;
            smf[rl * MERGE_STRIDE + p] = m2[ti * 4 + r];
            ssf[rl * MERGE_STRIDE + p] = s[ti * 4 + r];
        }
    __syncthreads();
    if (tid < TM) {
        float M = -INFINITY;
#pragma unroll
        for (int x = 0; x < 32; ++x) M = fmaxf(M, smf[tid * MERGE_STRIDE + x]);
        float S = 0.0f;
#pragma unroll
        for (int x = 0; x < 32; ++x)
            S += ssf[tid * MERGE_STRIDE + x]
               * __builtin_amdgcn_exp2f(smf[tid * MERGE_STRIDE + x] - M);
        part_m[(size_t)(rowBase + tid) * NSLICE + slice] = M;
        part_s[(size_t)(rowBase + tid) * NSLICE + slice] = S;
    }
}

// Kernel F: fused pos-dot + slice combine + loss reduce. Wave-per-row:
// 1024 blocks x 256 threads (4 rows/block), coalesced float4 dot + butterfly.
__global__ __launch_bounds__(256) void final_kernel(
    const float* __restrict__ z,
    const float* __restrict__ part_m, const float* __restrict__ part_s,
    float* __restrict__ acc_ct, float* __restrict__ out)
{
    __shared__ float red[4];
    const int tid = threadIdx.x;
    const int wv = tid >> 6, lane = tid & 63;
    const int i = blockIdx.x * 4 + wv;          // row 0..4095 (wave-uniform)
    float local = 0.0f;
    if ((i & 255) != 255) {                     // valid pair (also guards i=4095)
        // exact fp32 dot(z[i], z[i+1]): one float4 per lane, full-wave butterfly
        const float4 av = ((const float4*)(z + (size_t)i * DIM))[lane];
        const float4 bv = ((const float4*)(z + (size_t)(i + 1) * DIM))[lane];
        float d = av.x * bv.x + av.y * bv.y + av.z * bv.z + av.w * bv.w;
#pragma unroll
        for (int off = 32; off > 0; off >>= 1) d += __shfl_xor(d, off);
        // slice merge on lanes 0..15
        const float m  = (lane < NSLICE) ? part_m[(size_t)i * NSLICE + lane] : -INFINITY;
        const float sv = (lane < NSLICE) ? part_s[(size_t)i * NSLICE + lane] : 0.0f;
        float M = m;
#pragma unroll
        for (int off = 8; off > 0; off >>= 1) M = fmaxf(M, __shfl_xor(M, off));
        float S = (lane < NSLICE) ? sv * __builtin_amdgcn_exp2f(m - M) : 0.0f;
#pragma unroll
        for (int off = 8; off > 0; off >>= 1) S += __shfl_xor(S, off);
        const float lse = LN2 * (M + __builtin_amdgcn_logf(S));  // v_log = log2
        local = lse - d * INV_T;
    }
    if (lane == 0) red[wv] = local;
    __syncthreads();
    if (tid == 0) {
        const float r = red[0] + red[1] + red[2] + red[3];
        atomicAdd(&acc_ct[0], r);               // device-scope float atomic
        __threadfence();
        const unsigned old = atomicAdd((unsigned*)&acc_ct[1], 1u);
        if (old == gridDim.x - 1) {
            const float total = atomicAdd(&acc_ct[0], 0.0f);  // coherent read
            out[0] = total / 4080.0f;           // B*(L-1) valid pairs
        }
    }
}

extern "C" void kernel_launch(void* const* d_in, const int* in_sizes, int n_in,
                              void* d_out, int out_size, void* d_ws, size_t ws_size,
                              hipStream_t stream) {
    const float* z   = (const float*)d_in[0];   // [4096, 256]
    // d_in[1] = va_values: dead code in the reference, unused.
    const float* mem = (const float*)d_in[2];   // [16384, 256]

    // ws layout: cand bf16 [20480*256] | part_m f32 [4096*16]
    //          | part_s f32 [4096*16] | acc_ct f32[2]
    ushort_t* cand = (ushort_t*)d_ws;
    float* part_m  = (float*)(cand + (size_t)NCAND * DIM);
    float* part_s  = part_m + (size_t)NROWS * NSLICE;
    float* acc_ct  = part_s + (size_t)NROWS * NSLICE;

    const int castBlocks = NCAND * DIM / 4 / 256;   // 5120
    cast_kernel<<<dim3(castBlocks), dim3(256), 0, stream>>>(z, mem, cand, acc_ct);
    mfma_lse_kernel<<<dim3(NROWS / TM, NSLICE), dim3(256), 0, stream>>>(
        cand, part_m, part_s);
    final_kernel<<<dim3(NROWS / 4), dim3(256), 0, stream>>>(
        z, part_m, part_s, acc_ct, (float*)d_out);
}

// Round 8
// 151.246 us; speedup vs baseline: 1.2304x; 1.0492x over previous
//
#include <hip/hip_runtime.h>
#include <hip/hip_bf16.h>
#include <math.h>

// Problem constants (B=16, L=256, D=256, K=16384)
#define NROWS 4096               // B*L anchors / z rows
#define KMEM  16384
#define NCAND 20480              // NROWS + KMEM candidates
#define DIM   256                // feature dim
#define TM    128                // anchor rows per block
#define TN    128                // candidate cols per tile
#define BK    64                 // k-depth per LDS stage (bf16)
#define NSLICE 16                // 32 rowblocks x 16 slices = 512 blocks = 2/CU
#define COLS_PER_SLICE (NCAND / NSLICE)       // 1280
#define TILES_PER_SLICE (COLS_PER_SLICE / TN) // 10, uniform
#define INV_T  (1.0f / 0.07f)
#define SCALE2 (1.4426950408889634f / 0.07f)  // log2(e)/T
#define LN2    0.6931471805599453f
#define MERGE_STRIDE 33          // conflict-free merge: (tid*33+x)%32 distinct

typedef short  short8 __attribute__((ext_vector_type(8)));  // 8 bf16 (4 VGPRs)
typedef float  f32x4  __attribute__((ext_vector_type(4)));  // MFMA C/D
typedef unsigned short ushort_t;

// RNE float->bf16 (inputs are finite normals; no NaN path needed)
__device__ inline ushort_t f2bf(float x) {
    union { float f; unsigned u; } a; a.f = x;
    unsigned r = a.u + 0x7fff + ((a.u >> 16) & 1);
    return (ushort_t)(r >> 16);
}

// async global->LDS, 16B per lane, dest = wave-uniform base + lane*16
__device__ inline void load_lds16(const void* g, void* l) {
    __builtin_amdgcn_global_load_lds(
        (const __attribute__((address_space(1))) unsigned int*)g,
        (__attribute__((address_space(3))) unsigned int*)l, 16, 0, 0);
}

// Kernel 0: cast fp32 -> bf16 into cand = [z ; mem]; zero loss accumulator.
__global__ __launch_bounds__(256) void cast_kernel(
    const float* __restrict__ z, const float* __restrict__ mem,
    ushort_t* __restrict__ cand, float* __restrict__ acc_ct)
{
    if (blockIdx.x == 0 && threadIdx.x == 0) {
        acc_ct[0] = 0.0f;                      // loss accumulator
        ((unsigned*)acc_ct)[1] = 0u;           // arrival counter
    }
    const int idx = blockIdx.x * 256 + threadIdx.x;  // float4 index, < 1310720
    const int ZQ = NROWS * DIM / 4;                  // 262144
    const float4 v = (idx < ZQ) ? ((const float4*)z)[idx]
                                : ((const float4*)mem)[idx - ZQ];
    ushort4 u; u.x = f2bf(v.x); u.y = f2bf(v.y); u.z = f2bf(v.z); u.w = f2bf(v.w);
    ((ushort4*)cand)[idx] = u;
}

// Kernel A: double-buffered MFMA flash-LSE — the measured-best R0 structure,
// restored verbatim. 40-stage software pipeline: at each BK=64 stage, FIRST
// issue next stage's global_load_lds into the other buffer, THEN this
// stage's 32 MFMAs, THEN one __syncthreads(). Per-tile softmax epilogue runs
// while next tile's loads fly. 2 blocks/CU (64KB LDS) overlap drains.
//
// Session ledger (rounds 1-7, all falsified against this baseline):
//  - 8-phase 256^2 schedule: -19% (K too short; 1 block/CU).
//  - XCD-chunked swizzle: FETCH 41->12MB but -9% time (not latency-bound).
//  - fusion via grid barrier / split-K finale: -60..-116us (atomic+tail cost).
//  - LDS 65536->66048: 1 block/CU cliff, 2x slower.
//  - A-panel in registers: VGPR spill (WRITE_SIZE 0.6->16.9MB), -18%.
// Remaining headroom is softmax-VALU (~22us) vs MFMA (~17us) overlap; every
// cheap lever measured and rejected.
__global__ __launch_bounds__(256) void mfma_lse_kernel(
    const ushort_t* __restrict__ cand,
    float* __restrict__ part_m, float* __restrict__ part_s)
{
    __shared__ __align__(16) char smem_raw[65536];       // 2x(A 16KB + B 16KB)
    ushort_t* ldsA = (ushort_t*)smem_raw;                // [2][128*64]
    ushort_t* ldsB = ldsA + 2 * TM * BK;                 // [2][128*64]

    const int tid  = threadIdx.x;
    const int lane = tid & 63;
    const int w    = tid >> 6;        // wave 0..3
    const int wr   = w >> 1;          // wave row half (0/1)
    const int wc   = w & 1;           // wave col half
    const int quad = lane >> 4;
    const int ln   = lane & 15;
    const int rowBase = blockIdx.x * TM;
    const int slice   = blockIdx.y;
    const int colSliceBase = slice * COLS_PER_SLICE;

    // Staging geometry (loop-invariant): wave w covers tile rows
    // [w*32, w*32+32), lane l -> row srow + u*8, chunk c = (l&7)^(srow&7)
    // (invariant across u since u*8 = 0 mod 8). XOR swizzle keeps fragment
    // ds_read_b128 conflict-free.
    const int srow = w * 32 + (lane >> 3);
    const int sc   = (lane & 7) ^ (srow & 7);
    const ushort_t* agp    = cand + (size_t)(rowBase + srow) * DIM + sc * 8;
    const ushort_t* bgbase = cand + (size_t)(colSliceBase + srow) * DIM + sc * 8;
    ushort_t* lab = ldsA + (w * 32) * BK;   // + buf*TM*BK + u*8*BK
    ushort_t* lbb = ldsB + (w * 32) * BK;

    // issue one stage's 8 async loads (tile t, k-offset kk, buffer buf)
    auto stage = [&](int t, int kk, int buf) {
        const ushort_t* ag = agp + kk;
        const ushort_t* bg = bgbase + t * (TN * DIM) + kk;
        ushort_t* la = lab + buf * (TM * BK);
        ushort_t* lb = lbb + buf * (TM * BK);
#pragma unroll
        for (int u = 0; u < 4; ++u) {
            load_lds16(ag + u * 8 * DIM, la + u * 8 * BK);
            load_lds16(bg + u * 8 * DIM, lb + u * 8 * BK);
        }
    };

    float m2[16], s[16];
#pragma unroll
    for (int i = 0; i < 16; ++i) { m2[i] = -INFINITY; s[i] = 0.0f; }

    f32x4 acc[4][4];
#pragma unroll
    for (int ti = 0; ti < 4; ++ti)
#pragma unroll
        for (int tj = 0; tj < 4; ++tj) acc[ti][tj] = (f32x4)0.0f;

    stage(0, 0, 0);        // prologue: stage 0 -> buffer 0
    __syncthreads();

    for (int t = 0; t < TILES_PER_SLICE; ++t) {
#pragma unroll
        for (int q = 0; q < 4; ++q) {
            const int buf = q & 1;          // s = 4t+q -> buf = s&1 = q&1
            // prefetch next stage into the other buffer (in flight across
            // this stage's compute; drained by the barrier below)
            if (q < 3)                       stage(t,     (q + 1) * BK, buf ^ 1);
            else if (t + 1 < TILES_PER_SLICE) stage(t + 1, 0,           buf ^ 1);

            // compute stage s from buffer buf: 2 k-steps x 16 MFMA
            const ushort_t* la = ldsA + buf * (TM * BK);
            const ushort_t* lb = ldsB + buf * (TM * BK);
#pragma unroll
            for (int ks = 0; ks < 2; ++ks) {
                short8 af[4], bfr[4];
#pragma unroll
                for (int ti = 0; ti < 4; ++ti) {
                    const int row = wr * 64 + ti * 16 + ln;
                    const int p = row * 8 + ((ks * 4 + quad) ^ (row & 7));
                    af[ti] = *(const short8*)(la + p * 8);
                }
#pragma unroll
                for (int tj = 0; tj < 4; ++tj) {
                    const int col = wc * 64 + tj * 16 + ln;
                    const int p = col * 8 + ((ks * 4 + quad) ^ (col & 7));
                    bfr[tj] = *(const short8*)(lb + p * 8);
                }
#pragma unroll
                for (int ti = 0; ti < 4; ++ti)
#pragma unroll
                    for (int tj = 0; tj < 4; ++tj)
                        acc[ti][tj] = __builtin_amdgcn_mfma_f32_16x16x32_bf16(
                            af[ti], bfr[tj], acc[ti][tj], 0, 0, 0);
            }

            if (q == 3) {
                // Epilogue for tile t (runs while tile t+1's loads fly).
                // C/D layout: col = ln+16*tj+64*wc, row = quad*4+reg+16*ti+64*wr
                const int colBase = colSliceBase + t * TN;
                const bool hasDiag =
                    (colBase < rowBase + TM) && (rowBase < colBase + TN);
#pragma unroll
                for (int ti = 0; ti < 4; ++ti) {
#pragma unroll
                    for (int r = 0; r < 4; ++r) {
                        const int idx = ti * 4 + r;
                        float v0 = acc[ti][0][r], v1 = acc[ti][1][r];
                        float v2 = acc[ti][2][r], v3 = acc[ti][3][r];
                        if (hasDiag) {
                            const int grow = rowBase + wr * 64 + ti * 16 + quad * 4 + r;
                            const int gc0  = colBase + wc * 64 + ln;
                            if (gc0      == grow) v0 = -3.0e38f;  // mask self
                            if (gc0 + 16 == grow) v1 = -3.0e38f;
                            if (gc0 + 32 == grow) v2 = -3.0e38f;
                            if (gc0 + 48 == grow) v3 = -3.0e38f;
                        }
                        const float tmax = fmaxf(fmaxf(v0, v1), fmaxf(v2, v3)) * SCALE2;
                        const float mo = m2[idx];
                        const float mn = fmaxf(mo, tmax);
                        const float sc2 = __builtin_amdgcn_exp2f(mo - mn);
                        s[idx] = s[idx] * sc2
                               + __builtin_amdgcn_exp2f(fmaf(v0, SCALE2, -mn))
                               + __builtin_amdgcn_exp2f(fmaf(v1, SCALE2, -mn))
                               + __builtin_amdgcn_exp2f(fmaf(v2, SCALE2, -mn))
                               + __builtin_amdgcn_exp2f(fmaf(v3, SCALE2, -mn));
                        m2[idx] = mn;
                        acc[ti][0][r] = 0.0f; acc[ti][1][r] = 0.0f;
                        acc[ti][2][r] = 0.0f; acc[ti][3][r] = 0.0f;
                    }
                }
            }
            __syncthreads();   // publishes prefetched stage; frees old buffer
        }
    }

    // Cross-lane merge: 32 partials per row (16 ln x 2 wc), stride-33 overlay
    // (conflict-free: (tid*33+x)%32 = (tid+x)%32). Loop barrier above already
    // separated the last compute from this smem reuse.
    float* smf = (float*)smem_raw;         // [128][33] m partials
    float* ssf = smf + TM * MERGE_STRIDE;  // [128][33] s partials
    const int p = wc * 16 + ln;
#pragma unroll
    for (int ti = 0; ti < 4; ++ti)
#pragma unroll
        for (int r = 0; r < 4; ++r) {
            const int rl = wr * 64 + ti * 16 + quad * 4 + r;
            smf[rl * MERGE_STRIDE + p] = m2[ti * 4 + r];
            ssf[rl * MERGE_STRIDE + p] = s[ti * 4 + r];
        }
    __syncthreads();
    if (tid < TM) {
        float M = -INFINITY;
#pragma unroll
        for (int x = 0; x < 32; ++x) M = fmaxf(M, smf[tid * MERGE_STRIDE + x]);
        float S = 0.0f;
#pragma unroll
        for (int x = 0; x < 32; ++x)
            S += ssf[tid * MERGE_STRIDE + x]
               * __builtin_amdgcn_exp2f(smf[tid * MERGE_STRIDE + x] - M);
        part_m[(size_t)(rowBase + tid) * NSLICE + slice] = M;
        part_s[(size_t)(rowBase + tid) * NSLICE + slice] = S;
    }
}

// Kernel F: fused pos-dot + slice combine + loss reduce. Wave-per-row:
// 1024 blocks x 256 threads (4 rows/block), coalesced float4 dot + butterfly
// (verified passing in R4/R7; strictly more parallel than the 16-block
// serial-dot version).
__global__ __launch_bounds__(256) void final_kernel(
    const float* __restrict__ z,
    const float* __restrict__ part_m, const float* __restrict__ part_s,
    float* __restrict__ acc_ct, float* __restrict__ out)
{
    __shared__ float red[4];
    const int tid = threadIdx.x;
    const int wv = tid >> 6, lane = tid & 63;
    const int i = blockIdx.x * 4 + wv;          // row 0..4095 (wave-uniform)
    float local = 0.0f;
    if ((i & 255) != 255) {                     // valid pair (also guards i=4095)
        // exact fp32 dot(z[i], z[i+1]): one float4 per lane, full-wave butterfly
        const float4 av = ((const float4*)(z + (size_t)i * DIM))[lane];
        const float4 bv = ((const float4*)(z + (size_t)(i + 1) * DIM))[lane];
        float d = av.x * bv.x + av.y * bv.y + av.z * bv.z + av.w * bv.w;
#pragma unroll
        for (int off = 32; off > 0; off >>= 1) d += __shfl_xor(d, off);
        // slice merge on lanes 0..15
        const float m  = (lane < NSLICE) ? part_m[(size_t)i * NSLICE + lane] : -INFINITY;
        const float sv = (lane < NSLICE) ? part_s[(size_t)i * NSLICE + lane] : 0.0f;
        float M = m;
#pragma unroll
        for (int off = 8; off > 0; off >>= 1) M = fmaxf(M, __shfl_xor(M, off));
        float S = (lane < NSLICE) ? sv * __builtin_amdgcn_exp2f(m - M) : 0.0f;
#pragma unroll
        for (int off = 8; off > 0; off >>= 1) S += __shfl_xor(S, off);
        const float lse = LN2 * (M + __builtin_amdgcn_logf(S));  // v_log = log2
        local = lse - d * INV_T;
    }
    if (lane == 0) red[wv] = local;
    __syncthreads();
    if (tid == 0) {
        const float r = red[0] + red[1] + red[2] + red[3];
        atomicAdd(&acc_ct[0], r);               // device-scope float atomic
        __threadfence();
        const unsigned old = atomicAdd((unsigned*)&acc_ct[1], 1u);
        if (old == gridDim.x - 1) {
            const float total = atomicAdd(&acc_ct[0], 0.0f);  // coherent read
            out[0] = total / 4080.0f;           // B*(L-1) valid pairs
        }
    }
}

extern "C" void kernel_launch(void* const* d_in, const int* in_sizes, int n_in,
                              void* d_out, int out_size, void* d_ws, size_t ws_size,
                              hipStream_t stream) {
    const float* z   = (const float*)d_in[0];   // [4096, 256]
    // d_in[1] = va_values: dead code in the reference, unused.
    const float* mem = (const float*)d_in[2];   // [16384, 256]

    // ws layout: cand bf16 [20480*256] | part_m f32 [4096*16]
    //          | part_s f32 [4096*16] | acc_ct f32[2]
    ushort_t* cand = (ushort_t*)d_ws;
    float* part_m  = (float*)(cand + (size_t)NCAND * DIM);
    float* part_s  = part_m + (size_t)NROWS * NSLICE;
    float* acc_ct  = part_s + (size_t)NROWS * NSLICE;

    const int castBlocks = NCAND * DIM / 4 / 256;   // 5120
    cast_kernel<<<dim3(castBlocks), dim3(256), 0, stream>>>(z, mem, cand, acc_ct);
    mfma_lse_kernel<<<dim3(NROWS / TM, NSLICE), dim3(256), 0, stream>>>(
        cand, part_m, part_s);
    final_kernel<<<dim3(NROWS / 4), dim3(256), 0, stream>>>(
        z, part_m, part_s, acc_ct, (float*)d_out);
}